// Round 10
// baseline (100.558 us; speedup 1.0000x reference)
//
#include <hip/hip_runtime.h>

// phi (B,2,H,W) f32 -> out (B,1,H,W) f32 ; splat ones with bilinear weights, wrap BC.
// Gather formulation, tent weights, RB=4 multi-row amortization, store-only commit
// (exclusive ownership -> no commit atomics, no output memset), compile-time-pruned
// (t,m) pairs, packed-fp32 (VOP3P) col tents + slot accumulate.
// Wide-displacement sources (|dx|>=3 or |dy|>=3, P~0.5%) handled via per-(srow,chunk)
// byte flags (plain stores, no atomics -- R7/R8: contended counter == 900us wall) and
// a wave-batched flush kernel with scattered atomics (~360K, uncontended).
constexpr int H = 2048, W = 2048;
constexpr int HW = H * W;
constexpr int OUTW = 56;                    // output cols per wave (64 lanes - 8 halo)
constexpr int NCH = (W + OUTW - 1) / OUTW;  // 37 col-chunks (last ragged)
constexpr int RB  = 4;                      // owned rows per wave (proven no-spill)
constexpr int WPB = 4;                      // waves per block
constexpr int ROWSPB = RB * WPB;            // 16 rows per block
constexpr int NSRC = RB + 6;                // 10 scanned source rows per wave

typedef float f32x2 __attribute__((ext_vector_type(2)));

// tent(d) = max(1-|d|, 0) per half; |d| = max(d,-d) -> v_pk_max_f32 with neg modifier
__device__ __forceinline__ f32x2 pk_tent(f32x2 d) {
    f32x2 a = __builtin_elementwise_max(d, -d);
    f32x2 t = (f32x2)(1.0f) - a;
    return __builtin_elementwise_max(t, (f32x2)(0.0f));
}

__global__ __launch_bounds__(256)
void splat_gather4p(const float* __restrict__ phi, float* __restrict__ out,
                    unsigned char* __restrict__ flags) {
    int wid  = threadIdx.x >> 6;
    int lane = threadIdx.x & 63;

    const int rgPerImg = H / ROWSPB;        // 128
    int bid = blockIdx.x;
    int b   = bid / (NCH * rgPerImg);
    int rem = bid - b * (NCH * rgPerImg);
    int c0i = rem / rgPerImg;
    int rg  = rem - c0i * rgPerImg;
    int r0  = rg * ROWSPB + wid * RB;       // first owned row of this wave
    int c0  = c0i * OUTW;

    const float* phiB = phi + (size_t)b * 2 * HW;
    float* outb = out + (size_t)b * HW;

    int scu = c0 - 4 + lane;                // unwrapped source col of this lane
    int scw = scu & (W - 1);                // wrapped col for loads
    bool ownedCol = (lane >= 4) && (lane < 4 + OUTW) && (scu < W);

    // candidate source rows (loads sunk to first use by the compiler)
    float dxv[NSRC], dyv[NSRC];
    #pragma unroll
    for (int t = 0; t < NSRC; ++t) {
        int srow = (r0 + t - 3) & (H - 1);
        dxv[t] = phiB[(size_t)srow * W + scw];
        dyv[t] = phiB[(size_t)HW + (size_t)srow * W + scw];
    }

    // col-offset pairs: k in {-3..3} plus pad +4 (pad tent is identically 0 for |dy|<3)
    f32x2 slot[RB][4];
    #pragma unroll
    for (int m = 0; m < RB; ++m)
        #pragma unroll
        for (int p = 0; p < 4; ++p) slot[m][p] = (f32x2)(0.0f);

    #pragma unroll
    for (int t = 0; t < NSRC; ++t) {
        float dx = dxv[t], dy = dyv[t];
        bool valid = (__builtin_fabsf(dx) < 3.0f) && (__builtin_fabsf(dy) < 3.0f);
        float dyM = valid ? dy : 16384.0f;   // invalid -> all col tents 0 -> flush only

        // packed col tent weights toward offsets {2p-3, 2p-2}
        f32x2 dy2 = {dyM, dyM};
        f32x2 ct[4];
        #pragma unroll
        for (int p = 0; p < 4; ++p) {
            const f32x2 koff = {(float)(2 * p - 3), (float)(2 * p - 2)};
            ct[p] = pk_tent(dy2 - koff);
        }

        // row tents toward owned rows + rank-1 packed accumulate (rw==0 if |t-3-m|>=4)
        #pragma unroll
        for (int m = 0; m < RB; ++m) {
            if (t - m < 0 || t - m > 6) continue;   // compile-time DCE under unroll
            float dist = dx + (float)(t - 3 - m);   // x - (r0+m), unwrapped
            float rw = __builtin_fmaxf(1.0f - __builtin_fabsf(dist), 0.0f);
            f32x2 rw2 = {rw, rw};
            #pragma unroll
            for (int p = 0; p < 4; ++p)
                slot[m][p] = __builtin_elementwise_fma(rw2, ct[p], slot[m][p]);
        }

        // flag this wave's owned source rows (t in [3,3+RB)): plain byte store, no atomics
        if (t >= 3 && t < 3 + RB) {
            bool need = (!valid) && ownedCol;
            unsigned long long mask = __ballot(need);
            if (lane == 0) {
                int srow = (r0 + t - 3) & (H - 1);
                flags[(size_t)(b * H + srow) * NCH + c0i] = (mask != 0ull) ? 1 : 0;
            }
        }
    }

    // route column slots and commit with plain stores (exclusive ownership)
    // output col (c0+lane-4) pulls slot-half with offset ko from lane (lane-ko)
    #pragma unroll
    for (int m = 0; m < RB; ++m) {
        float v = 0.0f;
        #pragma unroll
        for (int p = 0; p < 4; ++p) {
            v += __shfl(slot[m][p].x, lane - (2 * p - 3));
            if (p < 3)
                v += __shfl(slot[m][p].y, lane - (2 * p - 2));
        }
        if (ownedCol)
            outb[(size_t)(r0 + m) * W + scu] = v;
    }
}

// Wave-batched flush: each wave reads 64 flags coalesced, processes flagged chunks.
__global__ __launch_bounds__(256)
void flush_flagged(const float* __restrict__ phi, const unsigned char* __restrict__ flags,
                   float* __restrict__ out) {
    int wid  = threadIdx.x >> 6;
    int lane = threadIdx.x & 63;
    unsigned base = ((unsigned)blockIdx.x * WPB + (unsigned)wid) * 64u;  // 64 chunks/wave

    unsigned char f = flags[base + (unsigned)lane];
    unsigned long long mask = __ballot(f != 0);

    while (mask) {
        int bit = (int)(__ffsll((long long)mask) - 1);
        mask &= mask - 1ull;
        unsigned chunk = base + (unsigned)bit;

        int c0i  = (int)(chunk % (unsigned)NCH);
        unsigned bs = chunk / (unsigned)NCH;
        int srow = (int)(bs & (H - 1));
        int b    = (int)(bs >> 11);            // H = 2048

        int col = c0i * OUTW + lane;           // lanes [0,56) own cols of this chunk
        if (lane < OUTW && col < W) {
            const float* phiB = phi + (size_t)b * 2 * HW;
            float dx = phiB[(size_t)srow * W + col];
            float dy = phiB[(size_t)HW + (size_t)srow * W + col];
            if (!((__builtin_fabsf(dx) < 3.0f) && (__builtin_fabsf(dy) < 3.0f))) {
                float* outb = out + (size_t)b * HW;
                float x = (float)srow + dx;
                float y = (float)col + dy;
                float x0 = floorf(x), y0 = floorf(y);
                float wx1 = x - x0, wx0 = 1.0f - wx1;
                float wy1 = y - y0, wy0 = 1.0f - wy1;
                int gx0 = ((int)x0) & (H - 1);
                int gx1 = (gx0 + 1) & (H - 1);
                int gy0 = ((int)y0) & (W - 1);
                int gy1 = (gy0 + 1) & (W - 1);
                atomicAdd(outb + (size_t)gx0 * W + gy0, wx0 * wy0);
                atomicAdd(outb + (size_t)gx0 * W + gy1, wx0 * wy1);
                atomicAdd(outb + (size_t)gx1 * W + gy0, wx1 * wy0);
                atomicAdd(outb + (size_t)gx1 * W + gy1, wx1 * wy1);
            }
        }
    }
}

extern "C" void kernel_launch(void* const* d_in, const int* in_sizes, int n_in,
                              void* d_out, int out_size, void* d_ws, size_t ws_size,
                              hipStream_t stream) {
    const float* phi = (const float*)d_in[0];
    float* out = (float*)d_out;
    unsigned char* flags = (unsigned char*)d_ws;   // B*H*NCH bytes, fully rewritten per call

    int B = out_size / HW;
    int grid = B * NCH * (H / ROWSPB);             // 4 * 37 * 128 = 18944 blocks
    splat_gather4p<<<grid, 256, 0, stream>>>(phi, out, flags);

    long long nChunks = (long long)B * H * NCH;    // 303,104 = 1184 * 256
    int grid2 = (int)(nChunks / (WPB * 64));       // 1184 blocks (64 chunks per wave)
    flush_flagged<<<grid2, 256, 0, stream>>>(phi, flags, out);
}

// Round 11
// 84.042 us; speedup vs baseline: 1.1965x; 1.1965x over previous
//
#include <hip/hip_runtime.h>

// phi (B,2,H,W) f32 -> out (B,1,H,W) f32 ; splat ones with bilinear weights, wrap BC.
// Gather formulation, SCALAR tent weights (VOP3P f32 is half-rate on gfx950 -- R10
// regression), RB=8 multi-row amortization with __launch_bounds__(256,2) for VGPR
// headroom (R7's spill was a budget artifact; counter wall masked RB=8's real perf),
// store-only commit (exclusive ownership -> no commit atomics, no output memset),
// compile-time-pruned (t,m) pairs. Wide-displacement sources (|dx|>=3 or |dy|>=3,
// P~0.5%) -> per-(srow,chunk) byte flags (plain stores; R7/R8: contended counter
// == 900us wall), flushed by a second kernel with scattered uncontended atomics.
constexpr int H = 2048, W = 2048;
constexpr int HW = H * W;
constexpr int OUTW = 56;                    // output cols per wave (64 lanes - 8 halo)
constexpr int NCH = (W + OUTW - 1) / OUTW;  // 37 col-chunks (last ragged)
constexpr int RB  = 8;                      // owned rows per wave
constexpr int WPB = 4;                      // waves per block
constexpr int ROWSPB = RB * WPB;            // 32 rows per block
constexpr int NSRC = RB + 6;                // 14 scanned source rows per wave

__global__ __launch_bounds__(256, 2)        // 2 waves/EU -> 256-VGPR budget, no spill
void splat_gather8s(const float* __restrict__ phi, float* __restrict__ out,
                    unsigned char* __restrict__ flags) {
    int wid  = threadIdx.x >> 6;
    int lane = threadIdx.x & 63;

    const int rgPerImg = H / ROWSPB;        // 64
    int bid = blockIdx.x;
    int b   = bid / (NCH * rgPerImg);
    int rem = bid - b * (NCH * rgPerImg);
    int c0i = rem / rgPerImg;
    int rg  = rem - c0i * rgPerImg;
    int r0  = rg * ROWSPB + wid * RB;       // first owned row of this wave
    int c0  = c0i * OUTW;

    const float* phiB = phi + (size_t)b * 2 * HW;
    float* outb = out + (size_t)b * HW;

    int scu = c0 - 4 + lane;                // unwrapped source col of this lane
    int scw = scu & (W - 1);                // wrapped col for loads
    bool ownedCol = (lane >= 4) && (lane < 4 + OUTW) && (scu < W);

    // candidate source rows (compiler sinks loads to first use)
    float dxv[NSRC], dyv[NSRC];
    #pragma unroll
    for (int t = 0; t < NSRC; ++t) {
        int srow = (r0 + t - 3) & (H - 1);
        dxv[t] = phiB[(size_t)srow * W + scw];
        dyv[t] = phiB[(size_t)HW + (size_t)srow * W + scw];
    }

    float slot[RB][7];
    #pragma unroll
    for (int m = 0; m < RB; ++m)
        #pragma unroll
        for (int k = 0; k < 7; ++k) slot[m][k] = 0.0f;

    #pragma unroll
    for (int t = 0; t < NSRC; ++t) {
        float dx = dxv[t], dy = dyv[t];
        bool valid = (__builtin_fabsf(dx) < 3.0f) && (__builtin_fabsf(dy) < 3.0f);
        float dyM = valid ? dy : 16384.0f;   // invalid -> all col tents 0 -> flush only

        // scalar col tent weights toward offsets ko = k-3 (shared across owned rows)
        float ct[7];
        #pragma unroll
        for (int k = 0; k < 7; ++k) {
            float d = dyM - (float)(k - 3);
            ct[k] = __builtin_fmaxf(1.0f - __builtin_fabsf(d), 0.0f);
        }

        // row tents toward owned rows + rank-1 accumulate (pruned: rw==0 if t-m not in [0,6])
        #pragma unroll
        for (int m = 0; m < RB; ++m) {
            if (t - m < 0 || t - m > 6) continue;   // compile-time DCE under unroll
            float dist = dx + (float)(t - 3 - m);   // x - (r0+m), unwrapped
            float rw = __builtin_fmaxf(1.0f - __builtin_fabsf(dist), 0.0f);
            #pragma unroll
            for (int k = 0; k < 7; ++k)
                slot[m][k] = __builtin_fmaf(rw, ct[k], slot[m][k]);
        }

        // flag this wave's owned source rows (t in [3,3+RB)): plain byte store, no atomics
        if (t >= 3 && t < 3 + RB) {
            bool need = (!valid) && ownedCol;
            unsigned long long mask = __ballot(need);
            if (lane == 0) {
                int srow = (r0 + t - 3) & (H - 1);
                flags[(size_t)(b * H + srow) * NCH + c0i] = (mask != 0ull) ? 1 : 0;
            }
        }
    }

    // route column slots and commit with plain stores (exclusive ownership)
    #pragma unroll
    for (int m = 0; m < RB; ++m) {
        float v = 0.0f;
        #pragma unroll
        for (int k = 0; k < 7; ++k)
            v += __shfl(slot[m][k], lane - (k - 3));
        if (ownedCol)
            outb[(size_t)(r0 + m) * W + scu] = v;
    }
}

// Wave-batched flush: each wave reads 16 flags, processes flagged chunks (full wave each).
__global__ __launch_bounds__(256)
void flush_flagged(const float* __restrict__ phi, const unsigned char* __restrict__ flags,
                   float* __restrict__ out) {
    int wid  = threadIdx.x >> 6;
    int lane = threadIdx.x & 63;
    unsigned base = ((unsigned)blockIdx.x * WPB + (unsigned)wid) * 16u;  // 16 chunks/wave

    unsigned char f = (lane < 16) ? flags[base + (unsigned)lane] : (unsigned char)0;
    unsigned long long mask = __ballot(f != 0);

    while (mask) {
        int bit = (int)(__ffsll((long long)mask) - 1);
        mask &= mask - 1ull;
        unsigned chunk = base + (unsigned)bit;

        int c0i  = (int)(chunk % (unsigned)NCH);
        unsigned bs = chunk / (unsigned)NCH;
        int srow = (int)(bs & (H - 1));
        int b    = (int)(bs >> 11);            // H = 2048

        int col = c0i * OUTW + lane;           // lanes [0,56) own cols of this chunk
        if (lane < OUTW && col < W) {
            const float* phiB = phi + (size_t)b * 2 * HW;
            float dx = phiB[(size_t)srow * W + col];
            float dy = phiB[(size_t)HW + (size_t)srow * W + col];
            if (!((__builtin_fabsf(dx) < 3.0f) && (__builtin_fabsf(dy) < 3.0f))) {
                float* outb = out + (size_t)b * HW;
                float x = (float)srow + dx;
                float y = (float)col + dy;
                float x0 = floorf(x), y0 = floorf(y);
                float wx1 = x - x0, wx0 = 1.0f - wx1;
                float wy1 = y - y0, wy0 = 1.0f - wy1;
                int gx0 = ((int)x0) & (H - 1);
                int gx1 = (gx0 + 1) & (H - 1);
                int gy0 = ((int)y0) & (W - 1);
                int gy1 = (gy0 + 1) & (W - 1);
                atomicAdd(outb + (size_t)gx0 * W + gy0, wx0 * wy0);
                atomicAdd(outb + (size_t)gx0 * W + gy1, wx0 * wy1);
                atomicAdd(outb + (size_t)gx1 * W + gy0, wx1 * wy0);
                atomicAdd(outb + (size_t)gx1 * W + gy1, wx1 * wy1);
            }
        }
    }
}

extern "C" void kernel_launch(void* const* d_in, const int* in_sizes, int n_in,
                              void* d_out, int out_size, void* d_ws, size_t ws_size,
                              hipStream_t stream) {
    const float* phi = (const float*)d_in[0];
    float* out = (float*)d_out;
    unsigned char* flags = (unsigned char*)d_ws;   // B*H*NCH bytes, fully rewritten per call

    int B = out_size / HW;
    int grid = B * NCH * (H / ROWSPB);             // 4 * 37 * 64 = 9472 blocks
    splat_gather8s<<<grid, 256, 0, stream>>>(phi, out, flags);

    long long nChunks = (long long)B * H * NCH;    // 303,104 = 4736 * 64
    int grid2 = (int)(nChunks / (WPB * 16));       // 4736 blocks (16 chunks per wave)
    flush_flagged<<<grid2, 256, 0, stream>>>(phi, flags, out);
}

// Round 12
// 83.162 us; speedup vs baseline: 1.2092x; 1.0106x over previous
//
#include <hip/hip_runtime.h>

// phi (B,2,H,W) f32 -> out (B,1,H,W) f32 ; splat ones with bilinear weights, wrap BC.
// Gather formulation, scalar tent weights (VOP3P f32 is half-rate on gfx950 -- R10),
// RB=8 multi-row amortization, store-only commit (exclusive ownership -> no commit
// atomics, no output memset), compile-time-pruned (t,m) pairs.
// R12: forced up-front prefetch (sched_barrier(0) stops load sinking -- one latency
// exposure per wave instead of 14) + 3 waves/EU occupancy for latency hiding.
// Wide-displacement sources (|dx|>=3 or |dy|>=3, P~0.5%) -> per-(srow,chunk) byte
// flags (plain stores; R7/R8: contended counter == 900us wall), flushed by a second
// kernel with scattered uncontended atomics.
constexpr int H = 2048, W = 2048;
constexpr int HW = H * W;
constexpr int OUTW = 56;                    // output cols per wave (64 lanes - 8 halo)
constexpr int NCH = (W + OUTW - 1) / OUTW;  // 37 col-chunks (last ragged)
constexpr int RB  = 8;                      // owned rows per wave
constexpr int WPB = 4;                      // waves per block
constexpr int ROWSPB = RB * WPB;            // 32 rows per block
constexpr int NSRC = RB + 6;                // 14 scanned source rows per wave

__global__ __launch_bounds__(256, 3)        // 3 waves/EU: 170-VGPR budget, ~110 live
void splat_gather8pf(const float* __restrict__ phi, float* __restrict__ out,
                     unsigned char* __restrict__ flags) {
    int wid  = threadIdx.x >> 6;
    int lane = threadIdx.x & 63;

    const int rgPerImg = H / ROWSPB;        // 64
    int bid = blockIdx.x;
    int b   = bid / (NCH * rgPerImg);
    int rem = bid - b * (NCH * rgPerImg);
    int c0i = rem / rgPerImg;
    int rg  = rem - c0i * rgPerImg;
    int r0  = rg * ROWSPB + wid * RB;       // first owned row of this wave
    int c0  = c0i * OUTW;

    const float* phiB = phi + (size_t)b * 2 * HW;
    float* outb = out + (size_t)b * HW;

    int scu = c0 - 4 + lane;                // unwrapped source col of this lane
    int scw = scu & (W - 1);                // wrapped col for loads
    bool ownedCol = (lane >= 4) && (lane < 4 + OUTW) && (scu < W);

    // prefetch ALL candidate source rows up front; sched_barrier pins the loads here
    float dxv[NSRC], dyv[NSRC];
    #pragma unroll
    for (int t = 0; t < NSRC; ++t) {
        int srow = (r0 + t - 3) & (H - 1);
        dxv[t] = phiB[(size_t)srow * W + scw];
        dyv[t] = phiB[(size_t)HW + (size_t)srow * W + scw];
    }
    __builtin_amdgcn_sched_barrier(0);      // forbid sinking loads into the t-loop

    float slot[RB][7];
    #pragma unroll
    for (int m = 0; m < RB; ++m)
        #pragma unroll
        for (int k = 0; k < 7; ++k) slot[m][k] = 0.0f;

    #pragma unroll
    for (int t = 0; t < NSRC; ++t) {
        float dx = dxv[t], dy = dyv[t];
        bool valid = (__builtin_fabsf(dx) < 3.0f) && (__builtin_fabsf(dy) < 3.0f);
        float dyM = valid ? dy : 16384.0f;   // invalid -> all col tents 0 -> flush only

        // scalar col tent weights toward offsets ko = k-3 (shared across owned rows)
        float ct[7];
        #pragma unroll
        for (int k = 0; k < 7; ++k) {
            float d = dyM - (float)(k - 3);
            ct[k] = __builtin_fmaxf(1.0f - __builtin_fabsf(d), 0.0f);
        }

        // row tents toward owned rows + rank-1 accumulate (pruned: rw==0 if t-m not in [0,6])
        #pragma unroll
        for (int m = 0; m < RB; ++m) {
            if (t - m < 0 || t - m > 6) continue;   // compile-time DCE under unroll
            float dist = dx + (float)(t - 3 - m);   // x - (r0+m), unwrapped
            float rw = __builtin_fmaxf(1.0f - __builtin_fabsf(dist), 0.0f);
            #pragma unroll
            for (int k = 0; k < 7; ++k)
                slot[m][k] = __builtin_fmaf(rw, ct[k], slot[m][k]);
        }

        // flag this wave's owned source rows (t in [3,3+RB)): plain byte store, no atomics
        if (t >= 3 && t < 3 + RB) {
            bool need = (!valid) && ownedCol;
            unsigned long long mask = __ballot(need);
            if (lane == 0) {
                int srow = (r0 + t - 3) & (H - 1);
                flags[(size_t)(b * H + srow) * NCH + c0i] = (mask != 0ull) ? 1 : 0;
            }
        }
    }

    // route column slots and commit with plain stores (exclusive ownership)
    #pragma unroll
    for (int m = 0; m < RB; ++m) {
        float v = 0.0f;
        #pragma unroll
        for (int k = 0; k < 7; ++k)
            v += __shfl(slot[m][k], lane - (k - 3));
        if (ownedCol)
            outb[(size_t)(r0 + m) * W + scu] = v;
    }
}

// Wave-batched flush: each wave reads 16 flags, processes flagged chunks (full wave each).
__global__ __launch_bounds__(256)
void flush_flagged(const float* __restrict__ phi, const unsigned char* __restrict__ flags,
                   float* __restrict__ out) {
    int wid  = threadIdx.x >> 6;
    int lane = threadIdx.x & 63;
    unsigned base = ((unsigned)blockIdx.x * WPB + (unsigned)wid) * 16u;  // 16 chunks/wave

    unsigned char f = (lane < 16) ? flags[base + (unsigned)lane] : (unsigned char)0;
    unsigned long long mask = __ballot(f != 0);

    while (mask) {
        int bit = (int)(__ffsll((long long)mask) - 1);
        mask &= mask - 1ull;
        unsigned chunk = base + (unsigned)bit;

        int c0i  = (int)(chunk % (unsigned)NCH);
        unsigned bs = chunk / (unsigned)NCH;
        int srow = (int)(bs & (H - 1));
        int b    = (int)(bs >> 11);            // H = 2048

        int col = c0i * OUTW + lane;           // lanes [0,56) own cols of this chunk
        if (lane < OUTW && col < W) {
            const float* phiB = phi + (size_t)b * 2 * HW;
            float dx = phiB[(size_t)srow * W + col];
            float dy = phiB[(size_t)HW + (size_t)srow * W + col];
            if (!((__builtin_fabsf(dx) < 3.0f) && (__builtin_fabsf(dy) < 3.0f))) {
                float* outb = out + (size_t)b * HW;
                float x = (float)srow + dx;
                float y = (float)col + dy;
                float x0 = floorf(x), y0 = floorf(y);
                float wx1 = x - x0, wx0 = 1.0f - wx1;
                float wy1 = y - y0, wy0 = 1.0f - wy1;
                int gx0 = ((int)x0) & (H - 1);
                int gx1 = (gx0 + 1) & (H - 1);
                int gy0 = ((int)y0) & (W - 1);
                int gy1 = (gy0 + 1) & (W - 1);
                atomicAdd(outb + (size_t)gx0 * W + gy0, wx0 * wy0);
                atomicAdd(outb + (size_t)gx0 * W + gy1, wx0 * wy1);
                atomicAdd(outb + (size_t)gx1 * W + gy0, wx1 * wy0);
                atomicAdd(outb + (size_t)gx1 * W + gy1, wx1 * wy1);
            }
        }
    }
}

extern "C" void kernel_launch(void* const* d_in, const int* in_sizes, int n_in,
                              void* d_out, int out_size, void* d_ws, size_t ws_size,
                              hipStream_t stream) {
    const float* phi = (const float*)d_in[0];
    float* out = (float*)d_out;
    unsigned char* flags = (unsigned char*)d_ws;   // B*H*NCH bytes, fully rewritten per call

    int B = out_size / HW;
    int grid = B * NCH * (H / ROWSPB);             // 4 * 37 * 64 = 9472 blocks
    splat_gather8pf<<<grid, 256, 0, stream>>>(phi, out, flags);

    long long nChunks = (long long)B * H * NCH;    // 303,104 = 4736 * 64
    int grid2 = (int)(nChunks / (WPB * 16));       // 4736 blocks (16 chunks per wave)
    flush_flagged<<<grid2, 256, 0, stream>>>(phi, flags, out);
}